// Round 4
// baseline (106.500 us; speedup 1.0000x reference)
//
#include <hip/hip_runtime.h>
#include <hip/hip_bf16.h>

// input_data:       (B=16, S=4096, C=256) fp32
// shifting_weights: (B=16, D=1024)        fp32
// output:           (B=16, D=1024, C=256) fp32
// out[b,d,c] = sum_s exp(-((s+1) - ((d+1)+w[b,d])*4)^2) / AMP * input[b,s,c]
//
// R4: register-streaming over G=8 consecutive d's per wave.
//  - Each wave streams the UNION window of its 8 Gaussian bands once
//    (~45-50 rows), applying all 8 weights per row: vector-memory traffic
//    drops from 17 KB/d (R2/R3) to ~5.6 KB/d -> ~92 MB total ~= compulsory
//    HBM traffic (67 MB input is read ~once).
//  - Manual 4x unroll keeps 4 independent 1 KB row-loads in flight per wave
//    (R1's one-load-per-roundtrip serialization was the killer of the shared
//    -window shape).
//  - Taps outside a d's own band underflow to exp(-large) = 0 -> branch-free.
//  - XCD-contiguous block swizzle (L2 locality) + non-temporal stores kept
//    from R3. 1/AMP folded into the epilogue.

constexpr int B = 16;
constexpr int S = 4096;
constexpr int C = 256;
constexpr int D = 1024;
constexpr float SCALING = (float)S / (float)D;   // 4.0
constexpr float INV_AMP = 1.0f / 1.772637204826652f;
constexpr float RADIUS  = 8.0f;
constexpr int G = 8;                 // d's per wave
constexpr int NUM_XCD = 8;

typedef float f32x4 __attribute__((ext_vector_type(4)));

__global__ __launch_bounds__(256) void shifting_kernel(
    const float* __restrict__ input,
    const float* __restrict__ wts,
    float* __restrict__ out)
{
    const int wave = threadIdx.x >> 6;
    const int lane = threadIdx.x & 63;

    // XCD-contiguity swizzle: physical block p runs on XCD p%8; give XCD x a
    // contiguous logical range so its 4 MiB L2 holds the sliding row window.
    const int per_xcd = gridDim.x >> 3;              // 512/8 = 64
    const int pblk = blockIdx.x;
    const int lblk = (pblk & (NUM_XCD - 1)) * per_xcd + (pblk >> 3);

    const int gidx0 = ((lblk << 2) + wave) * G;      // first flat b*D+d of wave
    const int b     = gidx0 >> 10;                   // / D
    const int d0    = gidx0 & (D - 1);               // aligned: all 8 d same b

    // Per-d Gaussian centers (wave-uniform values)
    float c[G];
#pragma unroll
    for (int i = 0; i < G; ++i) {
        float w = wts[gidx0 + i];
        c[i] = ((float)(d0 + i + 1) + w) * SCALING;
    }
    float cmin = c[0], cmax = c[0];
#pragma unroll
    for (int i = 1; i < G; ++i) {
        cmin = fminf(cmin, c[i]);
        cmax = fmaxf(cmax, c[i]);
    }
    const int s_lo = max(1, (int)ceilf(cmin - RADIUS));
    const int s_hi = min(S, (int)floorf(cmax + RADIUS));

    f32x4 acc[G];
#pragma unroll
    for (int i = 0; i < G; ++i) acc[i] = (f32x4){0.f, 0.f, 0.f, 0.f};

    const float* rowbase = input + ((size_t)b * S * C) + (lane << 2);

    int s = s_lo;
    // Main loop: 4 independent row loads in flight per iteration.
    for (; s + 3 <= s_hi; s += 4) {
        const float* p = rowbase + (size_t)(s - 1) * C;
        f32x4 v0 = *(const f32x4*)(p);
        f32x4 v1 = *(const f32x4*)(p + C);
        f32x4 v2 = *(const f32x4*)(p + 2 * C);
        f32x4 v3 = *(const f32x4*)(p + 3 * C);
#pragma unroll
        for (int i = 0; i < G; ++i) {
            float dd;
            dd = (float)(s + 0) - c[i]; acc[i] += __expf(-dd * dd) * v0;
            dd = (float)(s + 1) - c[i]; acc[i] += __expf(-dd * dd) * v1;
            dd = (float)(s + 2) - c[i]; acc[i] += __expf(-dd * dd) * v2;
            dd = (float)(s + 3) - c[i]; acc[i] += __expf(-dd * dd) * v3;
        }
    }
    // Tail
    for (; s <= s_hi; ++s) {
        f32x4 v = *(const f32x4*)(rowbase + (size_t)(s - 1) * C);
#pragma unroll
        for (int i = 0; i < G; ++i) {
            float dd = (float)s - c[i];
            acc[i] += __expf(-dd * dd) * v;
        }
    }

    // Epilogue: fold 1/AMP, non-temporal write-once stores.
    float* outbase = out + (size_t)gidx0 * C + (lane << 2);
#pragma unroll
    for (int i = 0; i < G; ++i) {
        f32x4 r = acc[i] * INV_AMP;
        __builtin_nontemporal_store(r, (f32x4*)(outbase + (size_t)i * C));
    }
}

extern "C" void kernel_launch(void* const* d_in, const int* in_sizes, int n_in,
                              void* d_out, int out_size, void* d_ws, size_t ws_size,
                              hipStream_t stream) {
    const float* input = (const float*)d_in[0];
    const float* wts   = (const float*)d_in[1];
    float* out         = (float*)d_out;

    dim3 grid(B * D / (4 * G));   // 512 blocks: 4 waves/block, 8 d's per wave
    dim3 block(256);
    shifting_kernel<<<grid, block, 0, stream>>>(input, wts, out);
}

// Round 5
// 99.592 us; speedup vs baseline: 1.0694x; 1.0694x over previous
//
#include <hip/hip_runtime.h>
#include <hip/hip_bf16.h>

// input_data:       (B=16, S=4096, C=256) fp32
// shifting_weights: (B=16, D=1024)        fp32
// output:           (B=16, D=1024, C=256) fp32
// out[b,d,c] = sum_s exp(-((s+1) - ((d+1)+w[b,d])*4)^2) / AMP * input[b,s,c]
//
// R5: G=2 d's/wave + register double-buffered streaming.
//  - G=2 keeps 8192 waves = 32/CU (R4's G=8 starved TLP at 8/CU and
//    regressed; R3's G=1 was best -> TLP is the binder, traffic second).
//  - Union window of the 2 bands (~23 rows avg) streamed once: vector-side
//    traffic 285 MB (R3) -> ~190 MB; excess over compulsory served by L2.
//  - Register double-buffer: preload next 4 rows BEFORE computing current 4,
//    keeping 4 KB/wave in flight across the waitcnt (R1/R4's per-iteration
//    load->wait->compute serialization removed).
//  - XCD-contiguous swizzle + non-temporal stores kept from R3.

constexpr int B = 16;
constexpr int S = 4096;
constexpr int C = 256;
constexpr int D = 1024;
constexpr float SCALING = (float)S / (float)D;   // 4.0
constexpr float INV_AMP = 1.0f / 1.772637204826652f;
constexpr float RADIUS  = 8.0f;
constexpr int G = 2;                 // d's per wave
constexpr int NUM_XCD = 8;

typedef float f32x4 __attribute__((ext_vector_type(4)));

__global__ __launch_bounds__(256) void shifting_kernel(
    const float* __restrict__ input,
    const float* __restrict__ wts,
    float* __restrict__ out)
{
    const int wave = threadIdx.x >> 6;
    const int lane = threadIdx.x & 63;

    // XCD-contiguity swizzle: physical block p runs on XCD p%8; give each XCD
    // a contiguous logical range so its 4 MiB L2 holds the sliding window.
    const int per_xcd = gridDim.x >> 3;              // 2048/8 = 256
    const int pblk = blockIdx.x;
    const int lblk = (pblk & (NUM_XCD - 1)) * per_xcd + (pblk >> 3);

    const int gidx0 = ((lblk << 2) + wave) * G;      // first flat b*D+d
    const int b     = gidx0 >> 10;                   // / D
    const int d0    = gidx0 & (D - 1);               // even: both d same b

    const float w0 = wts[gidx0];
    const float w1 = wts[gidx0 + 1];
    const float c0 = ((float)(d0 + 1) + w0) * SCALING;
    const float c1 = ((float)(d0 + 2) + w1) * SCALING;

    const float cmin = fminf(c0, c1);
    const float cmax = fmaxf(c0, c1);
    const int s_lo = max(1, (int)ceilf(cmin - RADIUS));
    const int s_hi = min(S, (int)floorf(cmax + RADIUS));

    const float* rb = input + ((size_t)b * S * C) + (lane << 2);
    // Clamped row load (rows past s_hi preloaded but never used; clamp keeps
    // addresses in-bounds).
    auto ldrow = [&](int r) -> f32x4 {
        return *(const f32x4*)(rb + (size_t)(min(r, S) - 1) * C);
    };

    f32x4 acc0 = {0.f, 0.f, 0.f, 0.f};
    f32x4 acc1 = {0.f, 0.f, 0.f, 0.f};

    int s = s_lo;
    f32x4 a0 = ldrow(s), a1 = ldrow(s + 1), a2 = ldrow(s + 2), a3 = ldrow(s + 3);

    for (; s + 3 <= s_hi; s += 4) {
        // Preload next batch first: stays in flight during this batch's math.
        f32x4 n0 = ldrow(s + 4), n1 = ldrow(s + 5),
              n2 = ldrow(s + 6), n3 = ldrow(s + 7);
        float dd;
        dd = (float)(s + 0) - c0; acc0 += __expf(-dd * dd) * a0;
        dd = (float)(s + 0) - c1; acc1 += __expf(-dd * dd) * a0;
        dd = (float)(s + 1) - c0; acc0 += __expf(-dd * dd) * a1;
        dd = (float)(s + 1) - c1; acc1 += __expf(-dd * dd) * a1;
        dd = (float)(s + 2) - c0; acc0 += __expf(-dd * dd) * a2;
        dd = (float)(s + 2) - c1; acc1 += __expf(-dd * dd) * a2;
        dd = (float)(s + 3) - c0; acc0 += __expf(-dd * dd) * a3;
        dd = (float)(s + 3) - c1; acc1 += __expf(-dd * dd) * a3;
        a0 = n0; a1 = n1; a2 = n2; a3 = n3;
    }
    // Tail (<4 rows): values already cached/in flight; reload is cheap.
    for (; s <= s_hi; ++s) {
        f32x4 v = ldrow(s);
        float dd;
        dd = (float)s - c0; acc0 += __expf(-dd * dd) * v;
        dd = (float)s - c1; acc1 += __expf(-dd * dd) * v;
    }

    float* outbase = out + (size_t)gidx0 * C + (lane << 2);
    f32x4 r0 = acc0 * INV_AMP;
    f32x4 r1 = acc1 * INV_AMP;
    __builtin_nontemporal_store(r0, (f32x4*)(outbase));
    __builtin_nontemporal_store(r1, (f32x4*)(outbase + C));
}

extern "C" void kernel_launch(void* const* d_in, const int* in_sizes, int n_in,
                              void* d_out, int out_size, void* d_ws, size_t ws_size,
                              hipStream_t stream) {
    const float* input = (const float*)d_in[0];
    const float* wts   = (const float*)d_in[1];
    float* out         = (float*)d_out;

    dim3 grid(B * D / (4 * G));   // 2048 blocks: 4 waves/block, 2 d's/wave
    dim3 block(256);
    shifting_kernel<<<grid, block, 0, stream>>>(input, wts, out);
}